// Round 2
// baseline (159.443 us; speedup 1.0000x reference)
//
#include <hip/hip_runtime.h>

typedef unsigned int u32;
typedef unsigned short u16;

#define N_BATCH 8192
#define EMB_DIM 128
#define MARGIN 1.0f
#define CAP 256          // max members per class (mean 128, sd ~11 -> 11 sigma)
#define BIGF 3.3e38f

typedef __attribute__((ext_vector_type(8))) short bf16x8;   // 8 bf16 = 4 VGPRs
typedef __attribute__((ext_vector_type(4))) float f32x4;    // MFMA 16x16 acc

// async global->LDS, 16B per lane; lds dest is wave-uniform base (+lane*16 implicit)
__device__ inline void async_ld16(const void* g, void* l) {
    __builtin_amdgcn_global_load_lds(
        (const __attribute__((address_space(1))) unsigned int*)g,
        (__attribute__((address_space(3))) unsigned int*)l, 16, 0, 0);
}

// ---------------------------------------------------------------------------
// Kernel 1: bf16 cast + row sq-norms + class bucketing.
// cnt[] zeroed by hipMemsetAsync before this kernel.
// ---------------------------------------------------------------------------
__global__ __launch_bounds__(256) void k_prep(const float* __restrict__ emb,
                                              const int* __restrict__ labels,
                                              u16* __restrict__ ebf,
                                              float* __restrict__ sq,
                                              u32* __restrict__ memb,
                                              u32* __restrict__ cnt) {
    int t = threadIdx.x;
    int r = blockIdx.x * 8 + (t >> 5);
    int l32 = t & 31;
    float4 x = ((const float4*)emb)[(size_t)r * 32 + l32];
    u32 ux = __float_as_uint(x.x), uy = __float_as_uint(x.y);
    u32 uz = __float_as_uint(x.z), uw = __float_as_uint(x.w);
    ushort4 b;
    b.x = (u16)((ux + 0x7fffu + ((ux >> 16) & 1u)) >> 16);
    b.y = (u16)((uy + 0x7fffu + ((uy >> 16) & 1u)) >> 16);
    b.z = (u16)((uz + 0x7fffu + ((uz >> 16) & 1u)) >> 16);
    b.w = (u16)((uw + 0x7fffu + ((uw >> 16) & 1u)) >> 16);
    ((ushort4*)ebf)[(size_t)r * 32 + l32] = b;

    float v = fmaf(x.x, x.x, fmaf(x.y, x.y, fmaf(x.z, x.z, x.w * x.w)));
    v += __shfl_down(v, 16, 64);   // 32-lane reduce
    v += __shfl_down(v, 8, 64);
    v += __shfl_down(v, 4, 64);
    v += __shfl_down(v, 2, 64);
    v += __shfl_down(v, 1, 64);
    if (l32 == 0) {
        sq[r] = v;
        int lb = labels[r];
        u32 p = atomicAdd(&cnt[lb], 1u);
        if (p < CAP) memb[(size_t)lb * CAP + p] = (u32)r;
    }
}

// ---------------------------------------------------------------------------
// Kernel 2: fused Gram + masked row/col min.  NO global atomics: block (bx,by)
// plain-stores row-mins to partmin[by][R..] and col-mins to partmin[bx][C..].
// Perfect partition: each of the 64 slots per row written exactly once.
// (verified round 1, absmax 0.0 — unchanged)
// ---------------------------------------------------------------------------
__global__ __launch_bounds__(256, 3) void k_gram(const u16* __restrict__ ebf,
                                                 const float* __restrict__ sq,
                                                 const int* __restrict__ labels,
                                                 float* __restrict__ partmin) {
    // ---- triangular decode: idx -> (bx, by), by >= bx
    int idx = blockIdx.x;
    float ff = (129.0f - sqrtf(16641.0f - 8.0f * (float)idx)) * 0.5f;
    int bx = (int)ff;
    if (bx > 63) bx = 63;
    while (bx > 0 && idx < bx * 64 - (bx * (bx - 1)) / 2) --bx;
    while (idx >= (bx + 1) * 64 - ((bx + 1) * bx) / 2) ++bx;
    int by = bx + idx - (bx * 64 - (bx * (bx - 1)) / 2);
    const int R = bx * 128, C = by * 128;
    const bool diag = (bx == by);

    __shared__ uint4 Bs[2048];            // 32 KB B tile (XOR swizzled via source)
    __shared__ float s_sqR[128], s_sqC[128];
    __shared__ int s_lbR[128], s_lbC[128];
    __shared__ float rowpart[2][128];     // cross-wave combine, plain stores
    __shared__ float colpart[2][128];

    const int t = threadIdx.x;
    const int lane = t & 63, w = t >> 6;
    const int c16 = lane & 15, quad = lane >> 4;
    const uint4* gE = (const uint4*)ebf;

    // stage B tile (rows C..C+127) via async DMA, swizzle folded into source addr
#pragma unroll
    for (int it = 0; it < 8; ++it) {
        int s = w * 512 + it * 64 + lane;
        int row = s >> 4, chPos = s & 15;
        int ch = chPos ^ (row & 15);
        async_ld16(gE + (size_t)(C + row) * 16 + ch, Bs + (w * 512 + it * 64));
    }
    // stage tile sq/labels (removes L2-latency stalls from the epilogue)
    if (t < 128) {
        s_sqR[t] = sq[R + t];
        s_lbR[t] = labels[R + t];
    } else {
        int t2 = t - 128;
        s_sqC[t2] = sq[C + t2];
        s_lbC[t2] = labels[C + t2];
    }

    const int mb = (w & 1) * 64;
    const int nb = (w >> 1) * 64;
    f32x4 acc[4][4];
#pragma unroll
    for (int i = 0; i < 4; ++i)
#pragma unroll
        for (int j = 0; j < 4; ++j) acc[i][j] = (f32x4){0.f, 0.f, 0.f, 0.f};

    const bf16x8* gA8 = (const bf16x8*)ebf;
    bf16x8 a[4];
#pragma unroll
    for (int i = 0; i < 4; ++i)
        a[i] = gA8[(size_t)(R + mb + i * 16 + c16) * 16 + quad];

    __syncthreads();   // drains LDS-DMA + sq/label stages

    const bf16x8* Bs8 = (const bf16x8*)Bs;
#pragma unroll
    for (int kc = 0; kc < 4; ++kc) {
        int kch = kc * 4 + quad;
        bf16x8 b[4];
#pragma unroll
        for (int j = 0; j < 4; ++j) {
            int br = nb + j * 16 + c16;
            b[j] = Bs8[br * 16 + (kch ^ (br & 15))];
        }
        bf16x8 an[4];
        if (kc < 3) {
            int kn = (kc + 1) * 4 + quad;
#pragma unroll
            for (int i = 0; i < 4; ++i)
                an[i] = gA8[(size_t)(R + mb + i * 16 + c16) * 16 + kn];
        }
#pragma unroll
        for (int i = 0; i < 4; ++i)
#pragma unroll
            for (int j = 0; j < 4; ++j)
                acc[i][j] = __builtin_amdgcn_mfma_f32_16x16x32_bf16(a[i], b[j], acc[i][j], 0, 0, 0);
        if (kc < 3) {
#pragma unroll
            for (int i = 0; i < 4; ++i) a[i] = an[i];
        }
    }

    // ---- epilogue: per-wave masked mins
    float cs_[4]; int cl_[4];
#pragma unroll
    for (int j = 0; j < 4; ++j) {
        int cc = nb + j * 16 + c16;
        cs_[j] = s_sqC[cc];
        cl_[j] = s_lbC[cc];
    }
    float cm[4] = {BIGF, BIGF, BIGF, BIGF};

#pragma unroll
    for (int i = 0; i < 4; ++i) {
        const int rowbase = mb + i * 16 + quad * 4;
        float rs_[4]; int rl_[4];
#pragma unroll
        for (int rg = 0; rg < 4; ++rg) {
            rs_[rg] = s_sqR[rowbase + rg];
            rl_[rg] = s_lbR[rowbase + rg];
        }
        float rm[4] = {BIGF, BIGF, BIGF, BIGF};
#pragma unroll
        for (int j = 0; j < 4; ++j) {
#pragma unroll
            for (int rg = 0; rg < 4; ++rg) {
                // C/D layout (m89/m91): D[row=quad*4+rg][col=lane&15]
                float d = fmaf(-2.f, acc[i][j][rg], rs_[rg] + cs_[j]);
                bool same = (rl_[rg] == cl_[j]);
                float cand = same ? BIGF : d;
                rm[rg] = fminf(rm[rg], cand);
                cm[j] = fminf(cm[j], cand);
            }
        }
#pragma unroll
        for (int rg = 0; rg < 4; ++rg) {
            float v = rm[rg];
            v = fminf(v, __shfl_xor(v, 1, 64));
            v = fminf(v, __shfl_xor(v, 2, 64));
            v = fminf(v, __shfl_xor(v, 4, 64));
            v = fminf(v, __shfl_xor(v, 8, 64));
            if (c16 == 0) rowpart[w >> 1][rowbase + rg] = v;  // plain store, disjoint slots
        }
    }
    if (!diag) {
#pragma unroll
        for (int j = 0; j < 4; ++j) {
            float v = cm[j];
            v = fminf(v, __shfl_xor(v, 16, 64));
            v = fminf(v, __shfl_xor(v, 32, 64));
            if (quad == 0) colpart[w & 1][nb + j * 16 + c16] = v;
        }
    }
    __syncthreads();

    if (t < 128) {
        float v = fminf(rowpart[0][t], rowpart[1][t]);
        partmin[(size_t)by * N_BATCH + R + t] = v;
    } else if (!diag) {
        int cc = t - 128;
        float v = fminf(colpart[0][cc], colpart[1][cc]);
        partmin[(size_t)bx * N_BATCH + C + cc] = v;
    }
}

// ---------------------------------------------------------------------------
// Kernel 3: per-class pair losses. No label scan (buckets from k_prep), no LDS
// tile (fragments straight from L2-hot ebf), partmin 64-deep fold inlined for
// members only. 32-row wave ownership -> all 4 waves busy at n~128.
// ---------------------------------------------------------------------------
__global__ __launch_bounds__(256) void k_class(const u16* __restrict__ ebf,
                                               const float* __restrict__ sq,
                                               const float* __restrict__ partmin,
                                               const u32* __restrict__ memb,
                                               const u32* __restrict__ cnt,
                                               float* __restrict__ totalsF,
                                               u32* __restrict__ totalsU,
                                               float* __restrict__ out) {
    const int c = blockIdx.x;
    __shared__ u32 lmem[CAP];
    __shared__ float lnm[CAP], lsq[CAP];
    __shared__ float redS[4], redC[4];

    const int t = threadIdx.x;
    const int lane = t & 63, w = t >> 6;
    const int c16 = lane & 15, quad = lane >> 4;

    int n = cnt[c]; if (n > CAP) n = CAP;

    if (t < n) {
        u32 r = memb[(size_t)c * CAP + t];
        lmem[t] = r;
        lsq[t] = sq[r];
        float v = partmin[r];                       // kk = 0
#pragma unroll 16
        for (int kk = 1; kk < 64; ++kk)
            v = fminf(v, partmin[(size_t)kk * N_BATCH + r]);
        lnm[t] = v;
    }
    __syncthreads();

    const bf16x8* gA8 = (const bf16x8*)ebf;
    float ssum = 0.f, scnt = 0.f;
    const int npan = (n + 63) >> 6;

    for (int rb = w * 32; rb < n; rb += 128) {      // 32 rows per wave per pass
        u32 ar[2];
#pragma unroll
        for (int i = 0; i < 2; ++i) {
            int rr = rb + i * 16 + c16;
            ar[i] = (rr < n) ? lmem[rr] : lmem[0];  // clamped rows masked below
        }
        float rc[2][4]; u32 opp[2][4];
#pragma unroll
        for (int i = 0; i < 2; ++i)
#pragma unroll
            for (int rg = 0; rg < 4; ++rg) {
                int p = rb + i * 16 + quad * 4 + rg;
                bool pv = (p < n);
                rc[i][rg] = pv ? (lsq[p] - lnm[p] + MARGIN) : -BIGF;
                opp[i][rg] = pv ? lmem[p] : 0xffffffffu;  // max sentinel: opp<oq never true
            }

        for (int cp = 0; cp < npan; ++cp) {
            u32 br[4], oq[4]; bool qv[4]; float lsqq[4];
#pragma unroll
            for (int j = 0; j < 4; ++j) {
                int q = cp * 64 + j * 16 + c16;
                qv[j] = (q < n);
                br[j] = qv[j] ? lmem[q] : lmem[0];
                oq[j] = qv[j] ? br[j] : 0u;         // 0 sentinel: opp<0 never true
                lsqq[j] = qv[j] ? lsq[q] : 0.f;
            }
            f32x4 acc[2][4];
#pragma unroll
            for (int i = 0; i < 2; ++i)
#pragma unroll
                for (int j = 0; j < 4; ++j) acc[i][j] = (f32x4){0.f, 0.f, 0.f, 0.f};
#pragma unroll
            for (int kc = 0; kc < 4; ++kc) {
                int kch = kc * 4 + quad;
                bf16x8 a[2], b[4];
#pragma unroll
                for (int i = 0; i < 2; ++i) a[i] = gA8[(size_t)ar[i] * 16 + kch];
#pragma unroll
                for (int j = 0; j < 4; ++j) b[j] = gA8[(size_t)br[j] * 16 + kch];
#pragma unroll
                for (int i = 0; i < 2; ++i)
#pragma unroll
                    for (int j = 0; j < 4; ++j)
                        acc[i][j] = __builtin_amdgcn_mfma_f32_16x16x32_bf16(a[i], b[j], acc[i][j], 0, 0, 0);
            }
#pragma unroll
            for (int i = 0; i < 2; ++i)
#pragma unroll
                for (int j = 0; j < 4; ++j)
#pragma unroll
                    for (int rg = 0; rg < 4; ++rg) {
                        float val = fmaf(-2.f, acc[i][j][rg], rc[i][rg] + lsqq[j]);
                        bool ok = qv[j] && (opp[i][rg] < oq[j]) && (val > 0.f);
                        if (ok) { ssum += val; scnt += 1.f; }
                    }
        }
    }

#pragma unroll
    for (int off = 32; off > 0; off >>= 1) {
        ssum += __shfl_down(ssum, off, 64);
        scnt += __shfl_down(scnt, off, 64);
    }
    if (lane == 0) { redS[w] = ssum; redC[w] = scnt; }
    __syncthreads();
    if (t == 0) {
        float S = redS[0] + redS[1] + redS[2] + redS[3];
        float Cc = redC[0] + redC[1] + redC[2] + redC[3];
        atomicAdd(&totalsF[0], S);
        atomicAdd(&totalsF[1], Cc);
        __threadfence();
        u32 tk = atomicAdd(&totalsU[3], 1u);
        if (tk == 63u) {                 // last class block: finalize
            __threadfence();
            float fs = atomicAdd(&totalsF[0], 0.f);
            float fc = atomicAdd(&totalsF[1], 0.f);
            out[0] = fs / fmaxf(fc, 1.0f);
        }
    }
}

// ---------------------------------------------------------------------------
extern "C" void kernel_launch(void* const* d_in, const int* in_sizes, int n_in,
                              void* d_out, int out_size, void* d_ws, size_t ws_size,
                              hipStream_t stream) {
    const float* emb = (const float*)d_in[0];
    const int* labels = (const int*)d_in[1];

    char* w = (char*)d_ws;
    u16* ebf = (u16*)w;
    size_t off = (size_t)N_BATCH * EMB_DIM * sizeof(u16);               // 2 MB
    float* sq = (float*)(w + off);      off += (size_t)N_BATCH * 4;     // 32 KB
    float* partmin = (float*)(w + off); off += (size_t)64 * N_BATCH * 4;// 2 MB
    u32* memb = (u32*)(w + off);        off += (size_t)64 * CAP * 4;    // 64 KB
    u32* cnt = (u32*)(w + off);         // cnt[64] then totals[...] in one 512B blob
    u32* totals = cnt + 64;

    hipMemsetAsync(cnt, 0, 512, stream);                       // cnt + totals
    k_prep<<<N_BATCH / 8, 256, 0, stream>>>(emb, labels, ebf, sq, memb, cnt);
    k_gram<<<2080, 256, 0, stream>>>(ebf, sq, labels, partmin);
    k_class<<<64, 256, 0, stream>>>(ebf, sq, partmin, memb, cnt,
                                    (float*)totals, totals, (float*)d_out);
}

// Round 3
// 125.463 us; speedup vs baseline: 1.2708x; 1.2708x over previous
//
#include <hip/hip_runtime.h>

typedef unsigned int u32;
typedef unsigned short u16;

#define N_BATCH 8192
#define EMB_DIM 128
#define MARGIN 1.0f
#define CAP 256          // max members per class (mean 128, sd ~11 -> 11 sigma)
#define BIGF 3.3e38f

typedef __attribute__((ext_vector_type(8))) short bf16x8;   // 8 bf16 = 4 VGPRs
typedef __attribute__((ext_vector_type(4))) float f32x4;    // MFMA 16x16 acc

// async global->LDS, 16B per lane; lds dest is wave-uniform base (+lane*16 implicit)
__device__ inline void async_ld16(const void* g, void* l) {
    __builtin_amdgcn_global_load_lds(
        (const __attribute__((address_space(1))) unsigned int*)g,
        (__attribute__((address_space(3))) unsigned int*)l, 16, 0, 0);
}

// ---------------------------------------------------------------------------
// Kernel 1: bf16 cast + row sq-norms + totals init. (round-1 verified, no memset)
// ---------------------------------------------------------------------------
__global__ __launch_bounds__(256) void k_prep(const float* __restrict__ emb,
                                              u16* __restrict__ ebf,
                                              float* __restrict__ sq,
                                              u32* __restrict__ totals) {
    int t = threadIdx.x;
    int g = blockIdx.x * 256 + t;
    int r = blockIdx.x * 8 + (t >> 5);
    int l32 = t & 31;
    float4 x = ((const float4*)emb)[(size_t)r * 32 + l32];
    u32 ux = __float_as_uint(x.x), uy = __float_as_uint(x.y);
    u32 uz = __float_as_uint(x.z), uw = __float_as_uint(x.w);
    ushort4 b;
    b.x = (u16)((ux + 0x7fffu + ((ux >> 16) & 1u)) >> 16);
    b.y = (u16)((uy + 0x7fffu + ((uy >> 16) & 1u)) >> 16);
    b.z = (u16)((uz + 0x7fffu + ((uz >> 16) & 1u)) >> 16);
    b.w = (u16)((uw + 0x7fffu + ((uw >> 16) & 1u)) >> 16);
    ((ushort4*)ebf)[(size_t)r * 32 + l32] = b;

    float v = fmaf(x.x, x.x, fmaf(x.y, x.y, fmaf(x.z, x.z, x.w * x.w)));
    v += __shfl_down(v, 16, 64);   // 32-lane reduce
    v += __shfl_down(v, 8, 64);
    v += __shfl_down(v, 4, 64);
    v += __shfl_down(v, 2, 64);
    v += __shfl_down(v, 1, 64);
    if (l32 == 0) sq[r] = v;
    if (g < 4) totals[g] = 0u;     // sumF, cntF, (unused), ticket  — NO memset!
}

// ---------------------------------------------------------------------------
// Kernel 2: fused Gram + masked row/col min. (round-1 verified, byte-identical)
// Block (bx,by) plain-stores row-mins to partmin[by][R..], col-mins to
// partmin[bx][C..] — perfect partition, zero atomics.
// ---------------------------------------------------------------------------
__global__ __launch_bounds__(256, 3) void k_gram(const u16* __restrict__ ebf,
                                                 const float* __restrict__ sq,
                                                 const int* __restrict__ labels,
                                                 float* __restrict__ partmin) {
    // ---- triangular decode: idx -> (bx, by), by >= bx
    int idx = blockIdx.x;
    float ff = (129.0f - sqrtf(16641.0f - 8.0f * (float)idx)) * 0.5f;
    int bx = (int)ff;
    if (bx > 63) bx = 63;
    while (bx > 0 && idx < bx * 64 - (bx * (bx - 1)) / 2) --bx;
    while (idx >= (bx + 1) * 64 - ((bx + 1) * bx) / 2) ++bx;
    int by = bx + idx - (bx * 64 - (bx * (bx - 1)) / 2);
    const int R = bx * 128, C = by * 128;
    const bool diag = (bx == by);

    __shared__ uint4 Bs[2048];            // 32 KB B tile (XOR swizzled via source)
    __shared__ float s_sqR[128], s_sqC[128];
    __shared__ int s_lbR[128], s_lbC[128];
    __shared__ float rowpart[2][128];     // cross-wave combine, plain stores
    __shared__ float colpart[2][128];

    const int t = threadIdx.x;
    const int lane = t & 63, w = t >> 6;
    const int c16 = lane & 15, quad = lane >> 4;
    const uint4* gE = (const uint4*)ebf;

    // stage B tile (rows C..C+127) via async DMA, swizzle folded into source addr
#pragma unroll
    for (int it = 0; it < 8; ++it) {
        int s = w * 512 + it * 64 + lane;
        int row = s >> 4, chPos = s & 15;
        int ch = chPos ^ (row & 15);
        async_ld16(gE + (size_t)(C + row) * 16 + ch, Bs + (w * 512 + it * 64));
    }
    // stage tile sq/labels (removes L2-latency stalls from the epilogue)
    if (t < 128) {
        s_sqR[t] = sq[R + t];
        s_lbR[t] = labels[R + t];
    } else {
        int t2 = t - 128;
        s_sqC[t2] = sq[C + t2];
        s_lbC[t2] = labels[C + t2];
    }

    const int mb = (w & 1) * 64;
    const int nb = (w >> 1) * 64;
    f32x4 acc[4][4];
#pragma unroll
    for (int i = 0; i < 4; ++i)
#pragma unroll
        for (int j = 0; j < 4; ++j) acc[i][j] = (f32x4){0.f, 0.f, 0.f, 0.f};

    const bf16x8* gA8 = (const bf16x8*)ebf;
    bf16x8 a[4];
#pragma unroll
    for (int i = 0; i < 4; ++i)
        a[i] = gA8[(size_t)(R + mb + i * 16 + c16) * 16 + quad];

    __syncthreads();   // drains LDS-DMA + sq/label stages

    const bf16x8* Bs8 = (const bf16x8*)Bs;
#pragma unroll
    for (int kc = 0; kc < 4; ++kc) {
        int kch = kc * 4 + quad;
        bf16x8 b[4];
#pragma unroll
        for (int j = 0; j < 4; ++j) {
            int br = nb + j * 16 + c16;
            b[j] = Bs8[br * 16 + (kch ^ (br & 15))];
        }
        bf16x8 an[4];
        if (kc < 3) {
            int kn = (kc + 1) * 4 + quad;
#pragma unroll
            for (int i = 0; i < 4; ++i)
                an[i] = gA8[(size_t)(R + mb + i * 16 + c16) * 16 + kn];
        }
#pragma unroll
        for (int i = 0; i < 4; ++i)
#pragma unroll
            for (int j = 0; j < 4; ++j)
                acc[i][j] = __builtin_amdgcn_mfma_f32_16x16x32_bf16(a[i], b[j], acc[i][j], 0, 0, 0);
        if (kc < 3) {
#pragma unroll
            for (int i = 0; i < 4; ++i) a[i] = an[i];
        }
    }

    // ---- epilogue: per-wave masked mins
    float cs_[4]; int cl_[4];
#pragma unroll
    for (int j = 0; j < 4; ++j) {
        int cc = nb + j * 16 + c16;
        cs_[j] = s_sqC[cc];
        cl_[j] = s_lbC[cc];
    }
    float cm[4] = {BIGF, BIGF, BIGF, BIGF};

#pragma unroll
    for (int i = 0; i < 4; ++i) {
        const int rowbase = mb + i * 16 + quad * 4;
        float rs_[4]; int rl_[4];
#pragma unroll
        for (int rg = 0; rg < 4; ++rg) {
            rs_[rg] = s_sqR[rowbase + rg];
            rl_[rg] = s_lbR[rowbase + rg];
        }
        float rm[4] = {BIGF, BIGF, BIGF, BIGF};
#pragma unroll
        for (int j = 0; j < 4; ++j) {
#pragma unroll
            for (int rg = 0; rg < 4; ++rg) {
                // C/D layout (m89/m91): D[row=quad*4+rg][col=lane&15]
                float d = fmaf(-2.f, acc[i][j][rg], rs_[rg] + cs_[j]);
                bool same = (rl_[rg] == cl_[j]);
                float cand = same ? BIGF : d;
                rm[rg] = fminf(rm[rg], cand);
                cm[j] = fminf(cm[j], cand);
            }
        }
#pragma unroll
        for (int rg = 0; rg < 4; ++rg) {
            float v = rm[rg];
            v = fminf(v, __shfl_xor(v, 1, 64));
            v = fminf(v, __shfl_xor(v, 2, 64));
            v = fminf(v, __shfl_xor(v, 4, 64));
            v = fminf(v, __shfl_xor(v, 8, 64));
            if (c16 == 0) rowpart[w >> 1][rowbase + rg] = v;  // plain store, disjoint slots
        }
    }
    if (!diag) {
#pragma unroll
        for (int j = 0; j < 4; ++j) {
            float v = cm[j];
            v = fminf(v, __shfl_xor(v, 16, 64));
            v = fminf(v, __shfl_xor(v, 32, 64));
            if (quad == 0) colpart[w & 1][nb + j * 16 + c16] = v;
        }
    }
    __syncthreads();

    if (t < 128) {
        float v = fminf(rowpart[0][t], rowpart[1][t]);
        partmin[(size_t)by * N_BATCH + R + t] = v;
    } else if (!diag) {
        int cc = t - 128;
        float v = fminf(colpart[0][cc], colpart[1][cc]);
        partmin[(size_t)bx * N_BATCH + C + cc] = v;
    }
}

// ---------------------------------------------------------------------------
// Kernel 3: per-class pair losses. Self-contained label scan (no global init
// needed), LDS-staged member rows, partmin 64-deep fold inlined (k_reduce
// deleted), 32-row wave ownership -> all 4 waves busy at n~128.
// ---------------------------------------------------------------------------
__global__ __launch_bounds__(256) void k_class(const u16* __restrict__ ebf,
                                               const float* __restrict__ sq,
                                               const int* __restrict__ labels,
                                               const float* __restrict__ partmin,
                                               float* __restrict__ totalsF,
                                               u32* __restrict__ totalsU,
                                               float* __restrict__ out) {
    const int c = blockIdx.x;
    __shared__ uint4 Es[4096];      // 64 KB: up to 256 member rows, XOR-swizzled
    __shared__ u32 lmem[CAP];
    __shared__ float lnm[CAP], lsq[CAP];
    __shared__ u32 lcount;
    __shared__ float redS[4], redC[4];

    const int t = threadIdx.x;
    const int lane = t & 63, w = t >> 6;
    const int c16 = lane & 15, quad = lane >> 4;

    if (t == 0) lcount = 0;
    __syncthreads();
    for (int r = t; r < N_BATCH; r += 256)
        if (labels[r] == c) {
            u32 p = atomicAdd(&lcount, 1u);
            if (p < CAP) lmem[p] = (u32)r;
        }
    __syncthreads();
    int n = lcount; if (n > CAP) n = CAP;
    const int npan = (n + 63) >> 6;          // 64-col panels actually needed

    const uint4* gE = (const uint4*)ebf;
    // gather only the n live rows (pad rows left as garbage; guarded below)
    for (int s = t; s < n * 16; s += 256) {
        int row = s >> 4, ch = s & 15;
        Es[row * 16 + (ch ^ (row & 15))] = gE[(size_t)lmem[row] * 16 + ch];
    }
    // per-member hardest-negative: fold the 64 partmin slots (scattered L2 reads)
    if (t < n) {
        u32 r = lmem[t];
        lsq[t] = sq[r];
        float v = partmin[r];                       // kk = 0
#pragma unroll 16
        for (int kk = 1; kk < 64; ++kk)
            v = fminf(v, partmin[(size_t)kk * N_BATCH + r]);
        lnm[t] = v;
    }
    __syncthreads();

    const bf16x8* Es8 = (const bf16x8*)Es;
    float ssum = 0.f, scnt = 0.f;

    for (int rb = w * 32; rb < n; rb += 128) {      // 32 rows per wave per pass
        float rc[2][4]; u32 opp[2][4];
#pragma unroll
        for (int i = 0; i < 2; ++i)
#pragma unroll
            for (int rg = 0; rg < 4; ++rg) {
                int p = rb + i * 16 + quad * 4 + rg;
                bool pv = (p < n);
                rc[i][rg] = pv ? (lsq[p] - lnm[p] + MARGIN) : -BIGF;
                opp[i][rg] = pv ? lmem[p] : 0xffffffffu;  // max sentinel: opp<oq never true
            }

        for (int cp = 0; cp < npan; ++cp) {
            u32 oq[4]; bool qv[4]; float lsqq[4];
#pragma unroll
            for (int j = 0; j < 4; ++j) {
                int q = cp * 64 + j * 16 + c16;
                qv[j] = (q < n);
                oq[j] = qv[j] ? lmem[q] : 0u;       // 0 sentinel: opp<0 never true
                lsqq[j] = qv[j] ? lsq[q] : 0.f;
            }
            f32x4 acc[2][4];
#pragma unroll
            for (int i = 0; i < 2; ++i)
#pragma unroll
                for (int j = 0; j < 4; ++j) acc[i][j] = (f32x4){0.f, 0.f, 0.f, 0.f};
#pragma unroll
            for (int kc = 0; kc < 4; ++kc) {
                int kch = kc * 4 + quad;
                bf16x8 a[2], b[4];
#pragma unroll
                for (int i = 0; i < 2; ++i) {
                    int ar = rb + i * 16 + c16;     // pad rows read LDS garbage; masked
                    a[i] = Es8[ar * 16 + (kch ^ (ar & 15))];
                }
#pragma unroll
                for (int j = 0; j < 4; ++j) {
                    int br = cp * 64 + j * 16 + c16;
                    b[j] = Es8[br * 16 + (kch ^ (br & 15))];
                }
#pragma unroll
                for (int i = 0; i < 2; ++i)
#pragma unroll
                    for (int j = 0; j < 4; ++j)
                        acc[i][j] = __builtin_amdgcn_mfma_f32_16x16x32_bf16(a[i], b[j], acc[i][j], 0, 0, 0);
            }
#pragma unroll
            for (int i = 0; i < 2; ++i)
#pragma unroll
                for (int j = 0; j < 4; ++j)
#pragma unroll
                    for (int rg = 0; rg < 4; ++rg) {
                        float val = fmaf(-2.f, acc[i][j][rg], rc[i][rg] + lsqq[j]);
                        bool ok = qv[j] && (opp[i][rg] < oq[j]) && (val > 0.f);
                        if (ok) { ssum += val; scnt += 1.f; }
                    }
        }
    }

#pragma unroll
    for (int off = 32; off > 0; off >>= 1) {
        ssum += __shfl_down(ssum, off, 64);
        scnt += __shfl_down(scnt, off, 64);
    }
    if (lane == 0) { redS[w] = ssum; redC[w] = scnt; }
    __syncthreads();
    if (t == 0) {
        float S = redS[0] + redS[1] + redS[2] + redS[3];
        float Cc = redC[0] + redC[1] + redC[2] + redC[3];
        atomicAdd(&totalsF[0], S);
        atomicAdd(&totalsF[1], Cc);
        __threadfence();
        u32 tk = atomicAdd(&totalsU[3], 1u);
        if (tk == 63u) {                 // last class block: finalize
            __threadfence();
            float fs = atomicAdd(&totalsF[0], 0.f);
            float fc = atomicAdd(&totalsF[1], 0.f);
            out[0] = fs / fmaxf(fc, 1.0f);
        }
    }
}

// ---------------------------------------------------------------------------
extern "C" void kernel_launch(void* const* d_in, const int* in_sizes, int n_in,
                              void* d_out, int out_size, void* d_ws, size_t ws_size,
                              hipStream_t stream) {
    const float* emb = (const float*)d_in[0];
    const int* labels = (const int*)d_in[1];

    char* w = (char*)d_ws;
    u16* ebf = (u16*)w;
    size_t off = (size_t)N_BATCH * EMB_DIM * sizeof(u16);               // 2 MB
    float* sq = (float*)(w + off);      off += (size_t)N_BATCH * 4;     // 32 KB
    float* partmin = (float*)(w + off); off += (size_t)64 * N_BATCH * 4;// 2 MB
    u32* totals = (u32*)(w + off);      off += 256;

    k_prep<<<N_BATCH / 8, 256, 0, stream>>>(emb, ebf, sq, totals);
    k_gram<<<2080, 256, 0, stream>>>(ebf, sq, labels, partmin);
    k_class<<<64, 256, 0, stream>>>(ebf, sq, labels, partmin,
                                    (float*)totals, totals, (float*)d_out);
}

// Round 4
// 118.880 us; speedup vs baseline: 1.3412x; 1.0554x over previous
//
#include <hip/hip_runtime.h>

typedef unsigned int u32;
typedef unsigned short u16;

#define N_BATCH 8192
#define EMB_DIM 128
#define MARGIN 1.0f
#define CAP 256          // max members per class (mean 128, sd ~11 -> 11 sigma)
#define BIGF 3.3e38f

typedef __attribute__((ext_vector_type(8))) short bf16x8;   // 8 bf16 = 4 VGPRs
typedef __attribute__((ext_vector_type(4))) float f32x4;    // MFMA 16x16 acc

// async global->LDS, 16B per lane; lds dest is wave-uniform base (+lane*16 implicit)
__device__ inline void async_ld16(const void* g, void* l) {
    __builtin_amdgcn_global_load_lds(
        (const __attribute__((address_space(1))) unsigned int*)g,
        (__attribute__((address_space(3))) unsigned int*)l, 16, 0, 0);
}

// ---------------------------------------------------------------------------
// Kernel 1: bf16 cast + row sq-norms + totals init. (round-1 verified)
// ---------------------------------------------------------------------------
__global__ __launch_bounds__(256) void k_prep(const float* __restrict__ emb,
                                              u16* __restrict__ ebf,
                                              float* __restrict__ sq,
                                              u32* __restrict__ totals) {
    int t = threadIdx.x;
    int g = blockIdx.x * 256 + t;
    int r = blockIdx.x * 8 + (t >> 5);
    int l32 = t & 31;
    float4 x = ((const float4*)emb)[(size_t)r * 32 + l32];
    u32 ux = __float_as_uint(x.x), uy = __float_as_uint(x.y);
    u32 uz = __float_as_uint(x.z), uw = __float_as_uint(x.w);
    ushort4 b;
    b.x = (u16)((ux + 0x7fffu + ((ux >> 16) & 1u)) >> 16);
    b.y = (u16)((uy + 0x7fffu + ((uy >> 16) & 1u)) >> 16);
    b.z = (u16)((uz + 0x7fffu + ((uz >> 16) & 1u)) >> 16);
    b.w = (u16)((uw + 0x7fffu + ((uw >> 16) & 1u)) >> 16);
    ((ushort4*)ebf)[(size_t)r * 32 + l32] = b;

    float v = fmaf(x.x, x.x, fmaf(x.y, x.y, fmaf(x.z, x.z, x.w * x.w)));
    v += __shfl_down(v, 16, 64);   // 32-lane reduce
    v += __shfl_down(v, 8, 64);
    v += __shfl_down(v, 4, 64);
    v += __shfl_down(v, 2, 64);
    v += __shfl_down(v, 1, 64);
    if (l32 == 0) sq[r] = v;
    if (g < 4) totals[g] = 0u;     // sumF, cntF, (unused), ticket  — NO memset!
}

// ---------------------------------------------------------------------------
// Kernel 2: fused Gram + masked row/col min. (round-1 verified core)
// ONLY change vs round 1: partmin layout transposed to [row][slot] so each
// row's 64 partials are contiguous (256 B) — kills the 32KB-stride channel
// aliasing in the consumer. Write-once partition unchanged.
// ---------------------------------------------------------------------------
__global__ __launch_bounds__(256, 3) void k_gram(const u16* __restrict__ ebf,
                                                 const float* __restrict__ sq,
                                                 const int* __restrict__ labels,
                                                 float* __restrict__ partmin) {
    // ---- triangular decode: idx -> (bx, by), by >= bx
    int idx = blockIdx.x;
    float ff = (129.0f - sqrtf(16641.0f - 8.0f * (float)idx)) * 0.5f;
    int bx = (int)ff;
    if (bx > 63) bx = 63;
    while (bx > 0 && idx < bx * 64 - (bx * (bx - 1)) / 2) --bx;
    while (idx >= (bx + 1) * 64 - ((bx + 1) * bx) / 2) ++bx;
    int by = bx + idx - (bx * 64 - (bx * (bx - 1)) / 2);
    const int R = bx * 128, C = by * 128;
    const bool diag = (bx == by);

    __shared__ uint4 Bs[2048];            // 32 KB B tile (XOR swizzled via source)
    __shared__ float s_sqR[128], s_sqC[128];
    __shared__ int s_lbR[128], s_lbC[128];
    __shared__ float rowpart[2][128];     // cross-wave combine, plain stores
    __shared__ float colpart[2][128];

    const int t = threadIdx.x;
    const int lane = t & 63, w = t >> 6;
    const int c16 = lane & 15, quad = lane >> 4;
    const uint4* gE = (const uint4*)ebf;

    // stage B tile (rows C..C+127) via async DMA, swizzle folded into source addr
#pragma unroll
    for (int it = 0; it < 8; ++it) {
        int s = w * 512 + it * 64 + lane;
        int row = s >> 4, chPos = s & 15;
        int ch = chPos ^ (row & 15);
        async_ld16(gE + (size_t)(C + row) * 16 + ch, Bs + (w * 512 + it * 64));
    }
    // stage tile sq/labels (removes L2-latency stalls from the epilogue)
    if (t < 128) {
        s_sqR[t] = sq[R + t];
        s_lbR[t] = labels[R + t];
    } else {
        int t2 = t - 128;
        s_sqC[t2] = sq[C + t2];
        s_lbC[t2] = labels[C + t2];
    }

    const int mb = (w & 1) * 64;
    const int nb = (w >> 1) * 64;
    f32x4 acc[4][4];
#pragma unroll
    for (int i = 0; i < 4; ++i)
#pragma unroll
        for (int j = 0; j < 4; ++j) acc[i][j] = (f32x4){0.f, 0.f, 0.f, 0.f};

    const bf16x8* gA8 = (const bf16x8*)ebf;
    bf16x8 a[4];
#pragma unroll
    for (int i = 0; i < 4; ++i)
        a[i] = gA8[(size_t)(R + mb + i * 16 + c16) * 16 + quad];

    __syncthreads();   // drains LDS-DMA + sq/label stages

    const bf16x8* Bs8 = (const bf16x8*)Bs;
#pragma unroll
    for (int kc = 0; kc < 4; ++kc) {
        int kch = kc * 4 + quad;
        bf16x8 b[4];
#pragma unroll
        for (int j = 0; j < 4; ++j) {
            int br = nb + j * 16 + c16;
            b[j] = Bs8[br * 16 + (kch ^ (br & 15))];
        }
        bf16x8 an[4];
        if (kc < 3) {
            int kn = (kc + 1) * 4 + quad;
#pragma unroll
            for (int i = 0; i < 4; ++i)
                an[i] = gA8[(size_t)(R + mb + i * 16 + c16) * 16 + kn];
        }
#pragma unroll
        for (int i = 0; i < 4; ++i)
#pragma unroll
            for (int j = 0; j < 4; ++j)
                acc[i][j] = __builtin_amdgcn_mfma_f32_16x16x32_bf16(a[i], b[j], acc[i][j], 0, 0, 0);
        if (kc < 3) {
#pragma unroll
            for (int i = 0; i < 4; ++i) a[i] = an[i];
        }
    }

    // ---- epilogue: per-wave masked mins
    float cs_[4]; int cl_[4];
#pragma unroll
    for (int j = 0; j < 4; ++j) {
        int cc = nb + j * 16 + c16;
        cs_[j] = s_sqC[cc];
        cl_[j] = s_lbC[cc];
    }
    float cm[4] = {BIGF, BIGF, BIGF, BIGF};

#pragma unroll
    for (int i = 0; i < 4; ++i) {
        const int rowbase = mb + i * 16 + quad * 4;
        float rs_[4]; int rl_[4];
#pragma unroll
        for (int rg = 0; rg < 4; ++rg) {
            rs_[rg] = s_sqR[rowbase + rg];
            rl_[rg] = s_lbR[rowbase + rg];
        }
        float rm[4] = {BIGF, BIGF, BIGF, BIGF};
#pragma unroll
        for (int j = 0; j < 4; ++j) {
#pragma unroll
            for (int rg = 0; rg < 4; ++rg) {
                // C/D layout (m89/m91): D[row=quad*4+rg][col=lane&15]
                float d = fmaf(-2.f, acc[i][j][rg], rs_[rg] + cs_[j]);
                bool same = (rl_[rg] == cl_[j]);
                float cand = same ? BIGF : d;
                rm[rg] = fminf(rm[rg], cand);
                cm[j] = fminf(cm[j], cand);
            }
        }
#pragma unroll
        for (int rg = 0; rg < 4; ++rg) {
            float v = rm[rg];
            v = fminf(v, __shfl_xor(v, 1, 64));
            v = fminf(v, __shfl_xor(v, 2, 64));
            v = fminf(v, __shfl_xor(v, 4, 64));
            v = fminf(v, __shfl_xor(v, 8, 64));
            if (c16 == 0) rowpart[w >> 1][rowbase + rg] = v;  // plain store, disjoint slots
        }
    }
    if (!diag) {
#pragma unroll
        for (int j = 0; j < 4; ++j) {
            float v = cm[j];
            v = fminf(v, __shfl_xor(v, 16, 64));
            v = fminf(v, __shfl_xor(v, 32, 64));
            if (quad == 0) colpart[w & 1][nb + j * 16 + c16] = v;
        }
    }
    __syncthreads();

    // transposed: row (R+t)'s slot `by` / row (C+cc)'s slot `bx`, contiguous per row
    if (t < 128) {
        float v = fminf(rowpart[0][t], rowpart[1][t]);
        partmin[(size_t)(R + t) * 64 + by] = v;
    } else if (!diag) {
        int cc = t - 128;
        float v = fminf(colpart[0][cc], colpart[1][cc]);
        partmin[(size_t)(C + cc) * 64 + bx] = v;
    }
}

// ---------------------------------------------------------------------------
// Kernel 3: per-class pair losses. (round-1 verified structure: label scan,
// Es staging, 64-row waves, npan bound.) Fold of the 64 partials is fused
// here — now 16 contiguous float4 loads per member (4 cache lines), replacing
// the deleted k_reduce launch.
// ---------------------------------------------------------------------------
__global__ __launch_bounds__(256) void k_class(const u16* __restrict__ ebf,
                                               const float* __restrict__ sq,
                                               const int* __restrict__ labels,
                                               const float* __restrict__ partmin,
                                               float* __restrict__ totalsF,
                                               u32* __restrict__ totalsU,
                                               float* __restrict__ out) {
    const int c = blockIdx.x;
    __shared__ uint4 Es[4096];      // 64 KB: up to 256 member rows, XOR-swizzled
    __shared__ u32 lmem[CAP];
    __shared__ float lnm[CAP], lsq[CAP];
    __shared__ u32 lcount;
    __shared__ float redS[4], redC[4];

    const int t = threadIdx.x;
    const int lane = t & 63, w = t >> 6;
    const int c16 = lane & 15, quad = lane >> 4;

    if (t == 0) lcount = 0;
    __syncthreads();
    for (int r = t; r < N_BATCH; r += 256)
        if (labels[r] == c) {
            u32 p = atomicAdd(&lcount, 1u);
            if (p < CAP) lmem[p] = (u32)r;
        }
    __syncthreads();
    int n = lcount; if (n > CAP) n = CAP;
    const int npan = (n + 63) >> 6;          // 64-col panels actually needed

    const uint4* gE = (const uint4*)ebf;
    // gather only the n live rows (pad rows left as garbage; guarded below)
    for (int s = t; s < n * 16; s += 256) {
        int row = s >> 4, ch = s & 15;
        Es[row * 16 + (ch ^ (row & 15))] = gE[(size_t)lmem[row] * 16 + ch];
    }
    // per-member hardest-negative: fold 64 contiguous partials (4 cache lines)
    if (t < n) {
        u32 r = lmem[t];
        lsq[t] = sq[r];
        const float4* pm4 = (const float4*)(partmin + (size_t)r * 64);
        float4 m0 = pm4[0];
        float4 acc4 = m0;
#pragma unroll
        for (int kk = 1; kk < 16; ++kk) {
            float4 mv = pm4[kk];
            acc4.x = fminf(acc4.x, mv.x);
            acc4.y = fminf(acc4.y, mv.y);
            acc4.z = fminf(acc4.z, mv.z);
            acc4.w = fminf(acc4.w, mv.w);
        }
        lnm[t] = fminf(fminf(acc4.x, acc4.y), fminf(acc4.z, acc4.w));
    }
    __syncthreads();

    const bf16x8* Es8 = (const bf16x8*)Es;
    float ssum = 0.f, scnt = 0.f;

    if (w * 64 < n) {                        // whole-wave row bound
        for (int cp = 0; cp < npan; ++cp) {  // col panels of 64
            f32x4 acc[4][4];
#pragma unroll
            for (int i = 0; i < 4; ++i)
#pragma unroll
                for (int j = 0; j < 4; ++j) acc[i][j] = (f32x4){0.f, 0.f, 0.f, 0.f};
#pragma unroll
            for (int kc = 0; kc < 4; ++kc) {
                int kch = kc * 4 + quad;
                bf16x8 a[4], b[4];
#pragma unroll
                for (int i = 0; i < 4; ++i) {
                    int ar = w * 64 + i * 16 + c16;
                    a[i] = Es8[ar * 16 + (kch ^ (ar & 15))];
                }
#pragma unroll
                for (int j = 0; j < 4; ++j) {
                    int br = cp * 64 + j * 16 + c16;
                    b[j] = Es8[br * 16 + (kch ^ (br & 15))];
                }
#pragma unroll
                for (int i = 0; i < 4; ++i) {
                    if (w * 64 + i * 16 >= n) continue;   // dead row-group
#pragma unroll
                    for (int j = 0; j < 4; ++j)
                        acc[i][j] = __builtin_amdgcn_mfma_f32_16x16x32_bf16(a[i], b[j], acc[i][j], 0, 0, 0);
                }
            }
            // epilogue for this 64x64 sub-tile
            float lsqq[4]; u32 oq[4]; bool qv[4];
#pragma unroll
            for (int j = 0; j < 4; ++j) {
                int q = cp * 64 + j * 16 + c16;
                qv[j] = (q < n);
                lsqq[j] = qv[j] ? lsq[q] : 0.f;
                oq[j] = qv[j] ? lmem[q] : 0u;            // 0 sentinel: opp<0 never true
            }
#pragma unroll
            for (int i = 0; i < 4; ++i) {
                if (w * 64 + i * 16 >= n) continue;
                int pb = w * 64 + i * 16 + quad * 4;
                float rcst[4]; u32 opp[4];
#pragma unroll
                for (int rg = 0; rg < 4; ++rg) {
                    int p = pb + rg;
                    bool pv = (p < n);
                    rcst[rg] = pv ? (lsq[p] - lnm[p] + MARGIN) : -BIGF;
                    opp[rg] = pv ? lmem[p] : 0xffffffffu; // max sentinel: opp<oq never true
                }
#pragma unroll
                for (int j = 0; j < 4; ++j)
#pragma unroll
                    for (int rg = 0; rg < 4; ++rg) {
                        float val = fmaf(-2.f, acc[i][j][rg], rcst[rg] + lsqq[j]);
                        bool ok = qv[j] && (opp[rg] < oq[j]) && (val > 0.f);
                        if (ok) { ssum += val; scnt += 1.f; }
                    }
            }
        }
    }

#pragma unroll
    for (int off = 32; off > 0; off >>= 1) {
        ssum += __shfl_down(ssum, off, 64);
        scnt += __shfl_down(scnt, off, 64);
    }
    if (lane == 0) { redS[w] = ssum; redC[w] = scnt; }
    __syncthreads();
    if (t == 0) {
        float S = redS[0] + redS[1] + redS[2] + redS[3];
        float Cc = redC[0] + redC[1] + redC[2] + redC[3];
        atomicAdd(&totalsF[0], S);
        atomicAdd(&totalsF[1], Cc);
        __threadfence();
        u32 tk = atomicAdd(&totalsU[3], 1u);
        if (tk == 63u) {                 // last class block: finalize
            __threadfence();
            float fs = atomicAdd(&totalsF[0], 0.f);
            float fc = atomicAdd(&totalsF[1], 0.f);
            out[0] = fs / fmaxf(fc, 1.0f);
        }
    }
}

// ---------------------------------------------------------------------------
extern "C" void kernel_launch(void* const* d_in, const int* in_sizes, int n_in,
                              void* d_out, int out_size, void* d_ws, size_t ws_size,
                              hipStream_t stream) {
    const float* emb = (const float*)d_in[0];
    const int* labels = (const int*)d_in[1];

    char* w = (char*)d_ws;
    u16* ebf = (u16*)w;
    size_t off = (size_t)N_BATCH * EMB_DIM * sizeof(u16);               // 2 MB
    float* sq = (float*)(w + off);      off += (size_t)N_BATCH * 4;     // 32 KB
    float* partmin = (float*)(w + off); off += (size_t)N_BATCH * 64 * 4;// 2 MB, [row][slot]
    u32* totals = (u32*)(w + off);      off += 256;

    k_prep<<<N_BATCH / 8, 256, 0, stream>>>(emb, ebf, sq, totals);
    k_gram<<<2080, 256, 0, stream>>>(ebf, sq, labels, partmin);
    k_class<<<64, 256, 0, stream>>>(ebf, sq, labels, partmin,
                                    (float*)totals, totals, (float*)d_out);
}